// Round 1
// baseline (68.703 us; speedup 1.0000x reference)
//
#include <hip/hip_runtime.h>
#include <math.h>

// Problem constants (fixed by setup_inputs)
#define B_     32
#define K_     16
#define T_     30
#define KT_    480      // K*T pred points per batch
#define N_     128
#define NPN_   20       // nodes per polyline
#define NODES_ 2560     // N*NPN per batch
#define CH_    16       // node chunks per batch (R7: 32 -> 16)
#define CSZ_   160      // nodes per chunk = 8 whole polylines (yaw local)

#define PI_F      3.14159265358979323846f
#define TWO_PI_F  6.28318530717958647692f
#define YAW_TH_F  (PI_F / 3.0f)
#define YAW_HI_F  (5.0f * PI_F / 3.0f)   // 2*pi - pi/3

// ws layout: float ws_part[B_][CH_][KT_]  (0.98 MB)
//
// Session journal (validated structure — do not re-try):
//  R3: single-kernel cross-block reduction via device-scope fence/atomics
//      costs ~60us on gfx950 (per-XCD L2 writeback). 2-kernel split is ~5us.
//  R5: ~50% nodes masked -> LDS compaction (order-free, min commutes). WIN.
//  R6: sqrt-deferral + wave early-exit + rare phase-2 fallback: REGRESSION.
//      Early exit needs all 128 pairs floored; phase-2 triggers ~23% of waves;
//      ballot broke unroll-8 scheduling. Loop is ISSUE-bound per 15-slot model.
//  R7 (this round): rocprof shows timed graph = 256MiB ws poison-fill (~40us,
//      FIXED harness floor, at 83% HBM peak) + our ~28us. cm_main's measured
//      cost is ~5x the pair-math issue model -> suspect per-block overheads
//      (32x-duplicated point atan2 prep, barriers, compaction, ramp).
//      Changes: (a) CH 32->16 / CSZ 80->160: halves per-block overhead at
//      constant pair work (occupancy 4->2 blocks/CU, tolerable since
//      issue-bound); (b) yaw clamp via v_med3_f32: med3(|d|-pi/3, 5pi/3-|d|, 0)
//      == relu(min(|d|, 2pi-|d|) - pi/3), both-negative impossible since
//      |d| < 2pi  -> saves 1 VALU/pair; (c) dual min-accumulators break the
//      8-deep dependent v_min chain in the unrolled body.

__global__ __launch_bounds__(256) void cm_main(
    const float* __restrict__ preds,   // (B, K, T, 2)
    const float* __restrict__ cn,      // (B, N, n, 2)
    const int*   __restrict__ cmask,   // (B, N, n)
    float*       __restrict__ ws_part) // (B, CH, KT)
{
  const int b   = blockIdx.x >> 4;          // / CH_
  const int c   = blockIdx.x & (CH_ - 1);
  const int tid = threadIdx.x;

  __shared__ float4 nd[CSZ_ + 8];   // compacted (-2x, -2y, a2, yaw) + inf pad
  __shared__ int    s_cnt;

  if (tid == 0) s_cnt = 0;
  __syncthreads();

  // ---- node prep + compaction (only unmasked nodes enter LDS) ----
  if (tid < CSZ_) {
    const int gn = c * CSZ_ + tid;
    const int mv = cmask[(size_t)b * NODES_ + gn];
    if (mv != 1) {
      const int j = gn % NPN_;
      const float2* cnb = (const float2*)cn + (size_t)b * NODES_;
      const float2 p = cnb[gn];
      float yaw = 0.0f;
      if (j != 0) {
        const float2 q = cnb[gn - 1];
        yaw = -atan2f(p.x - q.x, p.y - q.y);  // ref: -arctan2(dx, dy)
      }
      const float a2 = fmaf(p.x, p.x, p.y * p.y);
      const int pos = atomicAdd(&s_cnt, 1);   // LDS atomic, order-free for min
      nd[pos] = make_float4(-2.0f * p.x, -2.0f * p.y, a2, yaw);
    }
  }

  // ---- point prep in registers (2 points per thread) ----
  const int kt0 = tid;
  const int kt1 = tid + 256;                  // valid iff < 480
  const float2* pb = (const float2*)preds + (size_t)b * KT_;
  float4 p0, p1;
  {
    const float2 pp = pb[kt0];
    float pyaw = 0.0f;
    if ((kt0 % T_) != 0) {
      const float2 pq = pb[kt0 - 1];
      pyaw = -atan2f(pp.x - pq.x, pp.y - pq.y);
    }
    p0 = make_float4(pp.x, pp.y, fmaf(pp.x, pp.x, pp.y * pp.y), pyaw);
  }
  if (kt1 < KT_) {
    const float2 pp = pb[kt1];
    float pyaw = 0.0f;
    if ((kt1 % T_) != 0) {
      const float2 pq = pb[kt1 - 1];
      pyaw = -atan2f(pp.x - pq.x, pp.y - pq.y);
    }
    p1 = make_float4(pp.x, pp.y, fmaf(pp.x, pp.x, pp.y * pp.y), pyaw);
  } else {
    p1 = make_float4(0.f, 0.f, 0.f, 0.f);     // benign garbage lane
  }

  __syncthreads();
  const int cnt  = s_cnt;
  const int npad = (cnt + 7) & ~7;            // round up to unroll factor
  if (tid < npad - cnt)                       // inf sentinels: min no-ops
    nd[cnt + tid] = make_float4(0.f, 0.f, INFINITY, 0.f);
  __syncthreads();

  // ---- main min loop over compacted nodes ----
  // cost' = sqrt(max(d2,4)) + med3(|dyaw|-pi/3, 5pi/3-|dyaw|, 0)  [-2 hoisted]
  float m0a = INFINITY, m0b = INFINITY;
  float m1a = INFINITY, m1b = INFINITY;
  for (int i = 0; i < npad; i += 8) {
    #pragma unroll
    for (int j = 0; j < 8; ++j) {
      const float4 nv = nd[i + j];            // broadcast, conflict-free
      {
        float t = nv.z + p0.z;
        t = fmaf(nv.x, p0.x, t);
        t = fmaf(nv.y, p0.y, t);
        t = fmaxf(t, 4.0f);
        const float s  = __builtin_amdgcn_sqrtf(t);
        const float yd = fabsf(nv.w - p0.w);
        const float yc = __builtin_amdgcn_fmed3f(yd - YAW_TH_F,
                                                 YAW_HI_F - yd, 0.0f);
        const float v  = s + yc;
        if (j & 1) m0b = fminf(m0b, v); else m0a = fminf(m0a, v);
      }
      {
        float t = nv.z + p1.z;
        t = fmaf(nv.x, p1.x, t);
        t = fmaf(nv.y, p1.y, t);
        t = fmaxf(t, 4.0f);
        const float s  = __builtin_amdgcn_sqrtf(t);
        const float yd = fabsf(nv.w - p1.w);
        const float yc = __builtin_amdgcn_fmed3f(yd - YAW_TH_F,
                                                 YAW_HI_F - yd, 0.0f);
        const float v  = s + yc;
        if (j & 1) m1b = fminf(m1b, v); else m1a = fminf(m1a, v);
      }
    }
  }
  const float m0 = fminf(m0a, m0b);
  const float m1 = fminf(m1a, m1b);

  float* wp = ws_part + ((size_t)b * CH_ + c) * KT_;
  wp[kt0] = m0;
  if (kt1 < KT_) wp[kt1] = m1;
}

// Kernel 2: min over chunks (coalesced), subtract hoisted 2, sum over T.
__global__ __launch_bounds__(512) void cm_reduce(
    const float* __restrict__ ws_part, float* __restrict__ out)
{
  const int b   = blockIdx.x;
  const int tid = threadIdx.x;
  __shared__ float sc[KT_];

  if (tid < KT_) {
    const float* wp = ws_part + (size_t)b * CH_ * KT_;
    float m = INFINITY;
    #pragma unroll
    for (int c = 0; c < CH_; ++c) m = fminf(m, wp[c * KT_ + tid]);
    sc[tid] = m - 2.0f;                       // restore the hoisted -2
  }
  __syncthreads();

  if (tid < K_) {
    float s = 0.0f;
    #pragma unroll
    for (int t = 0; t < T_; ++t) s += sc[tid * T_ + t];
    out[b * K_ + tid] = s;
  }
}

extern "C" void kernel_launch(void* const* d_in, const int* in_sizes, int n_in,
                              void* d_out, int out_size, void* d_ws, size_t ws_size,
                              hipStream_t stream) {
  const float* preds = (const float*)d_in[0];
  const float* cn    = (const float*)d_in[1];
  const int*   cmask = (const int*)d_in[2];
  float* out = (float*)d_out;
  float* ws_part = (float*)d_ws;

  cm_main<<<dim3(B_ * CH_), dim3(256), 0, stream>>>(preds, cn, cmask, ws_part);
  cm_reduce<<<dim3(B_), dim3(512), 0, stream>>>(ws_part, out);
}